// Round 1
// baseline (419.233 us; speedup 1.0000x reference)
//
#include <hip/hip_runtime.h>
#include <math.h>

#define N_NODES 50000
#define KNEI    32
#define DIM     128
#define DOUT    128
#define MT      64      // nodes per block
#define KC      64      // K-chunk of the 512-wide cat row
#define AS_STRIDE 68    // padded LDS stride (68 % 32 == 4 -> conflict-light)

__global__ __launch_bounds__(256) void sage_fused(
    const float* __restrict__ fea1,
    const float* __restrict__ fea2,
    const int*   __restrict__ idx1,
    const int*   __restrict__ idx2,
    const float* __restrict__ W,
    float*       __restrict__ out)
{
    __shared__ float As[KC][AS_STRIDE];   // A-tile, transposed: As[k][m]
    __shared__ int   idxs[MT][64];        // [node][0:32]=list1, [32:64]=list2

    const int tid = threadIdx.x;
    const int n0  = blockIdx.x * MT;

    // ---- stage neighbor indices for the 64 nodes of this tile ----
    #pragma unroll
    for (int i = 0; i < 8; ++i) {
        int e  = tid + i * 256;           // 0..2047
        int m  = e >> 5;
        int kk = e & 31;
        int node = n0 + m;
        if (node >= N_NODES) node = N_NODES - 1;   // clamp; store is guarded later
        idxs[m][kk]      = idx1[node * KNEI + kk];
        idxs[m][32 + kk] = idx2[node * KNEI + kk];
    }

    float acc[8][4];
    #pragma unroll
    for (int i = 0; i < 8; ++i)
        #pragma unroll
        for (int j = 0; j < 4; ++j) acc[i][j] = 0.f;

    const int j0 = (tid & 31) * 4;        // output column base (0..124)
    const int m0 = (tid >> 5) * 8;        // output row base    (0..56)

    for (int c = 0; c < 8; ++c) {
        // ---------- stage A-tile for this K-chunk ----------
        if (c < 4) {
            // direct features: chunks 0-1 = fea1, 2-3 = fea2
            const float* src = (c < 2) ? fea1 : fea2;
            const int cbase = (c & 1) * 64;
            #pragma unroll
            for (int i = 0; i < 4; ++i) {
                int f  = tid + i * 256;   // 0..1023 float4s
                int m  = f >> 4;
                int c4 = (f & 15) * 4;
                int node = n0 + m;
                if (node >= N_NODES) node = N_NODES - 1;
                float4 v = *(const float4*)(src + node * DIM + cbase + c4);
                As[c4 + 0][m] = v.x;
                As[c4 + 1][m] = v.y;
                As[c4 + 2][m] = v.z;
                As[c4 + 3][m] = v.w;
            }
        } else {
            // neighbor-mean chunks: 4-5 = list1, 6-7 = list2
            const int col   = tid & 63;            // column within chunk
            const int kbase = (c & 1) * 64;        // column base within fea1 row
            const int lbase = (c < 6) ? 0 : 32;    // which neighbor list
            const int g     = tid >> 6;            // 0..3
            for (int mm = 0; mm < 16; ++mm) {
                const int m = g * 16 + mm;
                const int4* ip = (const int4*)&idxs[m][lbase];
                float s = 0.f;
                #pragma unroll
                for (int q = 0; q < 8; ++q) {
                    int4 nb = ip[q];
                    s += fea1[nb.x * DIM + kbase + col];
                    s += fea1[nb.y * DIM + kbase + col];
                    s += fea1[nb.z * DIM + kbase + col];
                    s += fea1[nb.w * DIM + kbase + col];
                }
                As[col][m] = s * (1.0f / 32.0f);
            }
        }
        __syncthreads();

        // ---------- GEMM over this K-chunk ----------
        const float* wp = W + (c * KC) * DOUT + j0;
        #pragma unroll 4
        for (int k = 0; k < KC; ++k) {
            float4 w = *(const float4*)(wp + k * DOUT);
            const float4* ap = (const float4*)&As[k][m0];
            float4 a0 = ap[0];
            float4 a1 = ap[1];
            float av[8] = {a0.x, a0.y, a0.z, a0.w, a1.x, a1.y, a1.z, a1.w};
            #pragma unroll
            for (int i = 0; i < 8; ++i) {
                acc[i][0] += av[i] * w.x;
                acc[i][1] += av[i] * w.y;
                acc[i][2] += av[i] * w.z;
                acc[i][3] += av[i] * w.w;
            }
        }
        __syncthreads();
    }

    // ---------- epilogue: tanh + store ----------
    #pragma unroll
    for (int i = 0; i < 8; ++i) {
        int node = n0 + m0 + i;
        if (node < N_NODES) {
            float4 r;
            r.x = tanhf(acc[i][0]);
            r.y = tanhf(acc[i][1]);
            r.z = tanhf(acc[i][2]);
            r.w = tanhf(acc[i][3]);
            *(float4*)(out + node * DOUT + j0) = r;
        }
    }
}

extern "C" void kernel_launch(void* const* d_in, const int* in_sizes, int n_in,
                              void* d_out, int out_size, void* d_ws, size_t ws_size,
                              hipStream_t stream) {
    const float* fea1 = (const float*)d_in[0];
    const float* fea2 = (const float*)d_in[1];
    const int*   idx1 = (const int*)d_in[2];
    const int*   idx2 = (const int*)d_in[3];
    const float* W    = (const float*)d_in[4];
    float* out = (float*)d_out;

    const int grid = (N_NODES + MT - 1) / MT;   // 782 blocks
    sage_fused<<<grid, 256, 0, stream>>>(fea1, fea2, idx1, idx2, W, out);
}